// Round 14
// baseline (48.768 us; speedup 1.0000x reference)
//
#include <hip/hip_runtime.h>
#include <math.h>

// ---------------------------------------------------------------------------
// ZBL repulsion, R14: atom-exclusive block ownership, 2 dispatches total.
//  - block b owns atoms [b*A, (b+1)*A), A = ceil(nA/NBLK) <= CAP slots;
//    pair range found by binary search on sorted idx_i (block-uniform)
//  - ALL deposits go to private LDS slots (no global atomics anywhere);
//    final mask/clip/nan/*0.01 epilogue folded into the block's own
//    plain stores (atoms without pairs correctly get 0)
//  - main loop = R13's depth-3 / unroll-2 register pipeline, barrier-free,
//    LDS z8 (100 KB) + za[256] tables, wave segmented scan on sorted keys
//  - native exp2/rcp/rsq lean math (validated absmax 2.4e-4)
// ---------------------------------------------------------------------------

#define LOG2E 1.4426950408889634f
#define BLK   1024
#define NBLK  256
#define STRD  (2 * BLK)
#define CAP   1024      // LDS slots per block; grid sized so atoms/block <= CAP

static __device__ __forceinline__ float rcpf_(float x)  { return __builtin_amdgcn_rcpf(x); }
static __device__ __forceinline__ float rsqf_(float x)  { return __builtin_amdgcn_rsqf(x); }
static __device__ __forceinline__ float exp2f_(float x) { return __builtin_amdgcn_exp2f(x); }
static __device__ __forceinline__ float log2f_(float x) { return __builtin_amdgcn_logf(x); }

struct f3 { float x, y, z; };
struct G  { int ii, jj; float bm, dx, dy, dz; };

__global__ void zbl_k0(const float* __restrict__ an,
                       unsigned char* __restrict__ z8, int n) {
    int i = blockIdx.x * blockDim.x + threadIdx.x;
    if (i >= n) return;
    int z = (int)(an[i] + 0.5f);
    z8[i] = (unsigned char)min(max(z, 1), 255);
}

static __device__ __forceinline__ G loadG(const int* __restrict__ idx_i,
                                          const int* __restrict__ idx_j,
                                          const float* __restrict__ bmk,
                                          const float* __restrict__ disp,
                                          int p, int cend) {
    G g; g.ii = -1; g.jj = 0; g.bm = 0.0f; g.dx = 0.0f; g.dy = 0.0f; g.dz = 0.0f;
    if (p < cend) {
        g.ii = idx_i[p];
        g.jj = idx_j[p];
        g.bm = bmk[p];
        f3 d = *reinterpret_cast<const f3*>(disp + (long)p * 3);
        g.dx = d.x; g.dy = d.y; g.dz = d.z;
    }
    return g;
}

static __device__ __forceinline__ int lower_bound_i(const int* __restrict__ arr,
                                                    int n, int val) {
    int lo = 0, hi = n;
    while (lo < hi) {
        int mid = (lo + hi) >> 1;
        if (arr[mid] < val) lo = mid + 1; else hi = mid;
    }
    return lo;
}

__global__ __launch_bounds__(BLK) void zbl_pair_kernel(
    const float* __restrict__ disp,
    const int*   __restrict__ idx_i,       // sorted
    const int*   __restrict__ idx_j,
    const float* __restrict__ batch_mask,
    const unsigned char* __restrict__ z8g,
    const float* __restrict__ atom_mask,
    const float* __restrict__ a_coef_ptr,
    const float* __restrict__ a_exp_ptr,
    const float* __restrict__ phi_c,
    const float* __restrict__ phi_e,
    float* __restrict__ out,               // [N] final output (plain stores)
    int nA, int nP, int aPerBlk)
{
    extern __shared__ unsigned char smem[];
    const int nA_pad = (nA + 15) & ~15;
    unsigned char* s_z8  = smem;                                // nA_pad B
    float*         s_za  = (float*)(smem + nA_pad);             // 256 f
    float*         s_acc = (float*)(smem + nA_pad + 1024);      // CAP f

    const int tid = threadIdx.x;

    // one-time: z8 table (coalesced uint4) + za table + zero slots
    {
        const int nw = nA >> 4;
        const uint4* g4 = reinterpret_cast<const uint4*>(z8g);
        uint4* s4 = reinterpret_cast<uint4*>(s_z8);
        for (int i = tid; i < nw; i += BLK) s4[i] = g4[i];
        for (int i = (nw << 4) + tid; i < nA; i += BLK) s_z8[i] = z8g[i];
    }
    if (tid < 256) {
        float ae = fabsf(a_exp_ptr[0]);
        int z = max(tid, 1);
        s_za[tid] = exp2f_(ae * log2f_((float)z));   // z^|ae|
    }
    for (int i = tid; i < CAP; i += BLK) s_acc[i] = 0.0f;

    // per-thread uniforms
    const float ac_inv = rcpf_(fmaxf(fabsf(a_coef_ptr[0]), 1e-10f));
    float c0 = fabsf(phi_c[0]), c1 = fabsf(phi_c[1]);
    float c2 = fabsf(phi_c[2]), c3 = fabsf(phi_c[3]);
    const float cinv = rcpf_(fmaxf(c0 + c1 + c2 + c3, 1e-10f));
    c0 *= cinv; c1 *= cinv; c2 *= cinv; c3 *= cinv;
    const float e0 = fmaxf(fabsf(phi_e[0]), 1e-10f);
    const float e1 = fmaxf(fabsf(phi_e[1]), 1e-10f);
    const float e2 = fmaxf(fabsf(phi_e[2]), 1e-10f);
    const float e3 = fmaxf(fabsf(phi_e[3]), 1e-10f);

    // ---- exclusive atom range -> pair range via binary search (uniform)
    const int aBeg = min((int)blockIdx.x * aPerBlk, nA);
    const int aEnd = min(aBeg + aPerBlk, nA);
    const int cbeg = lower_bound_i(idx_i, nP, aBeg);
    const int cend = lower_bound_i(idx_i, nP, aEnd);
    const int lane = tid & 63;

    __syncthreads();   // tables + slots ready

#define COMPUTE_G(g, rep, key)                                                  \
    {                                                                           \
        rep = 0.0f; key = -1;                                                   \
        if ((g).ii >= 0) {                                                      \
            const int zi = (int)s_z8[(g).ii];                                   \
            const int zj = (int)s_z8[(g).jj];                                   \
            const float za_i = s_za[zi];                                        \
            const float za_j = s_za[zj];                                        \
            const float add = 1.0f - (g).bm;                                    \
            const float dx = (g).dx + add, dy = (g).dy + add, dz = (g).dz + add;\
            float d2   = fmaxf(dx * dx + dy * dy + dz * dz, 1e-20f);            \
            float rsq  = rsqf_(d2);                                             \
            float dist = d2 * rsq;                                              \
            float tt = dist * 0.1f;                                             \
            float tc = fminf(fmaxf(tt, 1e-9f), 1.0f - 1e-9f);                   \
            float u  = (1.0f - 2.0f * tc) * rcpf_(tc - tc * tc);                \
            float s  = rcpf_(1.0f + exp2f_(u * LOG2E));                         \
            float sw = (tt >= 1.0f) ? 1.0f : s;                                 \
            float za_sum = za_i + za_j;                                         \
            float arg  = fminf(dist * za_sum * ac_inv, 1e6f);                   \
            float narg = -arg * LOG2E;                                          \
            float phi  = c0 * exp2f_(e0 * narg) + c1 * exp2f_(e1 * narg) +      \
                         c2 * exp2f_(e2 * narg) + c3 * exp2f_(e3 * narg);       \
            phi = fminf(fmaxf(phi, 1e-30f), 1e6f);                              \
            float cp   = fminf((float)(zi * zj), 1e4f);                         \
            float brep = fminf(0.5f * cp * rsq, 1e6f);                          \
            float r    = brep * phi * fmaxf(sw, 1e-30f);                        \
            r = fminf(fmaxf(r, 0.0f), 1e6f);                                    \
            if (!(r == r)) r = 0.0f;                                            \
            rep = r * (g).bm;                                                   \
            key = (g).ii;                                                       \
        }                                                                       \
    }

#define REDUCE_G(rep, key)                                                      \
    {                                                                           \
        const int k0_ = __shfl(key, 0);                                         \
        if (__all(key == k0_)) {                                                \
            float v = rep;                                                      \
            _Pragma("unroll")                                                   \
            for (int d = 1; d < 64; d <<= 1) v += __shfl_xor(v, d);             \
            if (lane == 0 && k0_ >= 0) atomicAdd(&s_acc[k0_ - aBeg], v);        \
        } else {                                                                \
            float v = rep;                                                      \
            int   k = key;                                                      \
            _Pragma("unroll")                                                   \
            for (int d = 1; d < 64; d <<= 1) {                                  \
                float nv = __shfl_down(v, d);                                   \
                int   nk = __shfl_down(k, d);                                   \
                if (lane + d < 64 && nk == k) v += nv;                          \
            }                                                                   \
            int pk = __shfl_up(k, 1);                                           \
            bool head = (lane == 0) || (pk != k);                               \
            if (head && k >= 0) atomicAdd(&s_acc[k - aBeg], v);                 \
        }                                                                       \
    }

    // ---- depth-3 / unroll-2 pipeline (R13's proven main loop)
    G a0 = loadG(idx_i, idx_j, batch_mask, disp, cbeg + tid,              cend);
    G b0 = loadG(idx_i, idx_j, batch_mask, disp, cbeg + BLK + tid,        cend);
    G a1 = loadG(idx_i, idx_j, batch_mask, disp, cbeg + STRD + tid,       cend);
    G b1 = loadG(idx_i, idx_j, batch_mask, disp, cbeg + STRD + BLK + tid, cend);

    for (int pb = cbeg; pb < cend; pb += STRD) {
        G a2 = loadG(idx_i, idx_j, batch_mask, disp, pb + 2 * STRD + tid,       cend);
        G b2 = loadG(idx_i, idx_j, batch_mask, disp, pb + 2 * STRD + BLK + tid, cend);

        float repA, repB; int keyA, keyB;
        COMPUTE_G(a0, repA, keyA);
        COMPUTE_G(b0, repB, keyB);
        REDUCE_G(repA, keyA);
        REDUCE_G(repB, keyB);

        a0 = a1; b0 = b1; a1 = a2; b1 = b2;
    }
#undef COMPUTE_G
#undef REDUCE_G

    // ---- folded epilogue: plain coalesced stores of owned atoms
    __syncthreads();
    for (int s = tid; s < aEnd - aBeg; s += BLK) {
        const int a = aBeg + s;
        float v = s_acc[s] * atom_mask[a];
        v = fminf(fmaxf(v, 0.0f), 1e6f);
        if (!(v == v)) v = 0.0f;
        out[a] = v * 0.01f;
    }
}

extern "C" void kernel_launch(void* const* d_in, const int* in_sizes, int n_in,
                              void* d_out, int out_size, void* d_ws, size_t ws_size,
                              hipStream_t stream) {
    const float* an         = (const float*)d_in[0];
    const float* disp       = (const float*)d_in[1];
    const int*   idx_i      = (const int*)d_in[2];
    const int*   idx_j      = (const int*)d_in[3];
    const float* atom_mask  = (const float*)d_in[4];
    const float* batch_mask = (const float*)d_in[5];
    const float* a_coef     = (const float*)d_in[8];
    const float* a_exp      = (const float*)d_in[9];
    const float* phi_c      = (const float*)d_in[10];
    const float* phi_e      = (const float*)d_in[11];

    const int nA = in_sizes[0];
    const int nP = in_sizes[2];
    float* out = (float*)d_out;

    unsigned char* z8 = (unsigned char*)d_ws;   // 100 KB, ws ample

    zbl_k0<<<(nA + 255) / 256, 256, 0, stream>>>(an, z8, nA);

    // grid sized so atoms/block <= CAP (391 for nA=100k at NBLK=256)
    int nblk = NBLK;
    int aPerBlk = (nA + nblk - 1) / nblk;
    if (aPerBlk > CAP) {                 // generality guard
        nblk = (nA + CAP - 1) / CAP;
        aPerBlk = CAP;
    }
    const int nA_pad = (nA + 15) & ~15;
    const size_t smem = (size_t)nA_pad + 1024 + (size_t)CAP * sizeof(float);
    zbl_pair_kernel<<<nblk, BLK, smem, stream>>>(
        disp, idx_i, idx_j, batch_mask, z8, atom_mask,
        a_coef, a_exp, phi_c, phi_e, out, nA, nP, aPerBlk);
}